// Round 6
// baseline (410.536 us; speedup 1.0000x reference)
//
#include <hip/hip_runtime.h>
#include <math.h>

// Node2GraphAttention: out[g] = sum_{i: batch[i]==g} sigmoid(<n_i, g_emb[g]>) * n_i
// N=500000, D=128, G=10000, n_batch sorted ascending.
//
// R6: TWO branch-light kernels instead of one branchy one (R3/R4/R5's
// fast/slow boundary branch was a scheduling wall: compiler wouldn't
// pipeline loads/shuffle chains across it -> all pipelining attempts null).
//
// K1 (coef): octet layout, 8 lanes/node, 16 cols/lane. 3-step shfl reduce,
//   NO branches in loop (g-row always reloaded; L2-hot), no accumulator.
//   Fully pipelinable. coefs[N] -> d_ws (2 MB).
// K2 (scatter): half-wave float4 layout, register acc + boundary atomic
//   flush, NO shuffles (coef is a broadcast load). Slow path is ~10 VALU ops.
// n_emb = 244 MiB < L3 256 MiB -> K2 re-read is L3-resident, so the
// two-pass structure costs ~HBM-once + L3-once, not 2x HBM.

#define BLOCKS 2048
#define BT 256

__device__ __forceinline__ float dot4(float4 a, float4 b) {
    return a.x * b.x + a.y * b.y + a.z * b.z + a.w * b.w;
}

// ---------------- K1: coefficients ----------------
__global__ __launch_bounds__(BT)
void coef_kernel(const float* __restrict__ n_emb,
                 const float* __restrict__ g_emb,
                 const int*   __restrict__ n_batch,
                 float* __restrict__ coefs,
                 int N)
{
    const int wave = blockIdx.x * (BT >> 6) + (threadIdx.x >> 6);
    const int lane = threadIdx.x & 63;
    const int oct  = lane >> 3;        // which of 8 nodes in the group
    const int l8   = lane & 7;         // position within octet
    const int col  = l8 * 16;          // 16 contiguous cols per lane
    const long num_waves = (long)BLOCKS * (BT >> 6);

    // 16 nodes (two independent 8-node groups) per iteration for ILP
    for (long base = (long)wave * 16; base < N; base += num_waves * 16) {
        const int nA = (int)min(base + oct,     (long)N - 1);
        const int nB = (int)min(base + 8 + oct, (long)N - 1);

        const int gA = n_batch[nA];
        const int gB = n_batch[nB];

        const float4* npA = (const float4*)(n_emb + (size_t)nA * 128 + col);
        const float4* npB = (const float4*)(n_emb + (size_t)nB * 128 + col);
        const float4* gpA = (const float4*)(g_emb + (size_t)gA * 128 + col);
        const float4* gpB = (const float4*)(g_emb + (size_t)gB * 128 + col);

        float4 nvA[4], nvB[4], gvA[4], gvB[4];
        #pragma unroll
        for (int t = 0; t < 4; ++t) { nvA[t] = npA[t]; nvB[t] = npB[t]; }
        #pragma unroll
        for (int t = 0; t < 4; ++t) { gvA[t] = gpA[t]; gvB[t] = gpB[t]; }

        float dA = 0.f, dB = 0.f;
        #pragma unroll
        for (int t = 0; t < 4; ++t) { dA += dot4(nvA[t], gvA[t]); dB += dot4(nvB[t], gvB[t]); }

        dA += __shfl_xor(dA, 1, 64);  dB += __shfl_xor(dB, 1, 64);
        dA += __shfl_xor(dA, 2, 64);  dB += __shfl_xor(dB, 2, 64);
        dA += __shfl_xor(dA, 4, 64);  dB += __shfl_xor(dB, 4, 64);

        const float cA = 1.0f / (1.0f + __expf(-dA));
        const float cB = 1.0f / (1.0f + __expf(-dB));

        if (l8 == 0) {
            if (base + oct     < N) coefs[nA] = cA;
            if (base + 8 + oct < N) coefs[nB] = cB;
        }
    }
}

// ---------------- K2: weighted scatter ----------------
#define U 8

#define FLUSH() do {                                              \
    atomicAdd(&out[(size_t)cur_g * 128 + col + 0], acc.x);        \
    atomicAdd(&out[(size_t)cur_g * 128 + col + 1], acc.y);        \
    atomicAdd(&out[(size_t)cur_g * 128 + col + 2], acc.z);        \
    atomicAdd(&out[(size_t)cur_g * 128 + col + 3], acc.w);        \
    acc = make_float4(0.f, 0.f, 0.f, 0.f);                        \
} while (0)

__global__ __launch_bounds__(BT)
void scatter_kernel(const float* __restrict__ n_emb,
                    const float* __restrict__ coefs,
                    const int*   __restrict__ n_batch,
                    float* __restrict__ out,
                    int N)
{
    const int hw_id  = blockIdx.x * (BT >> 5) + (threadIdx.x >> 5);
    const int l32    = threadIdx.x & 31;
    const int col    = l32 * 4;
    const int num_hw = BLOCKS * (BT >> 5);

    int per = (N + num_hw - 1) / num_hw;
    per = (per + 2 * U - 1) & ~(2 * U - 1);
    const int start = hw_id * per;
    if (start >= N) return;
    const int end = min(start + per, N);

    float4 acc = make_float4(0.f, 0.f, 0.f, 0.f);
    int cur_g = n_batch[start];

    int i = start;
    for (; i + U <= end; i += U) {
        const int4   b0 = *(const int4*)(n_batch + i);
        const int4   b1 = *(const int4*)(n_batch + i + 4);
        const float4 c0 = *(const float4*)(coefs + i);
        const float4 c1 = *(const float4*)(coefs + i + 4);

        float4 nv[U];
        #pragma unroll
        for (int j = 0; j < U; ++j)
            nv[j] = *(const float4*)(n_emb + (size_t)(i + j) * 128 + col);

        const float cc[U] = {c0.x, c0.y, c0.z, c0.w, c1.x, c1.y, c1.z, c1.w};

        if (b1.w == cur_g) {
            // whole group same graph (sorted): pure FMA
            #pragma unroll
            for (int j = 0; j < U; ++j) {
                acc.x += cc[j] * nv[j].x;
                acc.y += cc[j] * nv[j].y;
                acc.z += cc[j] * nv[j].z;
                acc.w += cc[j] * nv[j].w;
            }
        } else {
            const int bb[U] = {b0.x, b0.y, b0.z, b0.w, b1.x, b1.y, b1.z, b1.w};
            #pragma unroll
            for (int j = 0; j < U; ++j) {
                if (bb[j] != cur_g) { FLUSH(); cur_g = bb[j]; }
                acc.x += cc[j] * nv[j].x;
                acc.y += cc[j] * nv[j].y;
                acc.z += cc[j] * nv[j].z;
                acc.w += cc[j] * nv[j].w;
            }
        }
    }

    // scalar safety tail (empty for N=500000 with this grid)
    for (; i < end; ++i) {
        const int g = n_batch[i];
        const float c = coefs[i];
        const float4 nv = *(const float4*)(n_emb + (size_t)i * 128 + col);
        if (g != cur_g) { FLUSH(); cur_g = g; }
        acc.x += c * nv.x;
        acc.y += c * nv.y;
        acc.z += c * nv.z;
        acc.w += c * nv.w;
    }

    FLUSH();
}

extern "C" void kernel_launch(void* const* d_in, const int* in_sizes, int n_in,
                              void* d_out, int out_size, void* d_ws, size_t ws_size,
                              hipStream_t stream) {
    const float* n_emb   = (const float*)d_in[0];
    const float* g_emb   = (const float*)d_in[1];
    const int*   n_batch = (const int*)d_in[2];
    float* out   = (float*)d_out;
    float* coefs = (float*)d_ws;     // N floats = 2 MB, ws is >= 1 GB
    const int N = in_sizes[2];

    hipMemsetAsync(d_out, 0, (size_t)out_size * sizeof(float), stream);

    coef_kernel<<<BLOCKS, BT, 0, stream>>>(n_emb, g_emb, n_batch, coefs, N);
    scatter_kernel<<<BLOCKS, BT, 0, stream>>>(n_emb, coefs, n_batch, out, N);
}